// Round 1
// baseline (71.834 us; speedup 1.0000x reference)
//
#include <hip/hip_runtime.h>

// Bottom-up HTMM forward, fully fused: one block per (tree, generator).
// C=16 states, M=256 obs, L=2 positions, G=8 generators, 128 trees, depth 10.
#define C_     16
#define M_     256
#define G_     8
#define NT_    128
#define DEPTH_ 10
#define NPT_   1023   // nodes per tree

__device__ __forceinline__ float grpmax16(float v) {
  v = fmaxf(v, __shfl_xor(v, 1, 16));
  v = fmaxf(v, __shfl_xor(v, 2, 16));
  v = fmaxf(v, __shfl_xor(v, 4, 16));
  v = fmaxf(v, __shfl_xor(v, 8, 16));
  return v;
}
__device__ __forceinline__ float grpsum16(float v) {
  v += __shfl_xor(v, 1, 16);
  v += __shfl_xor(v, 2, 16);
  v += __shfl_xor(v, 4, 16);
  v += __shfl_xor(v, 8, 16);
  return v;
}

__global__ __launch_bounds__(256) void htmm_fwd_kernel(
    const float* __restrict__ lA,   // (16,16,2,8)
    const float* __restrict__ lB,   // (16,256,8)
    const float* __restrict__ lPi,  // (16,2,8)
    const float* __restrict__ lSP,  // (2,8)
    const int*   __restrict__ x,    // (128*1023,)
    float*       __restrict__ out)  // (128,8)
{
  __shared__ float sB[M_ * 17];       // normalized B, layout [m][c], pad 17
  __shared__ float sA[2 * 16 * 16];   // normalized A, layout [l][b][a]
  __shared__ float sPi[2 * 16];       // normalized Pi, layout [l][c]
  __shared__ float bufA[512 * 17];    // beliefs ping (leaf level), [node][17]
  __shared__ float bufB[256 * 17];    // beliefs pong
  __shared__ float red[4];

  const int tid = threadIdx.x;
  const int bid = blockIdx.x;         // = tree*8 + g
  const int T   = bid >> 3;
  const int g   = bid & 7;
  const int a   = tid & 15;           // hidden state owned by this lane
  const int grp = tid >> 4;           // 0..15, node-group id
  const long base = (long)T * NPT_;

  // ---- SP softmax (2 values, redundant per thread) ----
  float s0 = lSP[g], s1 = lSP[G_ + g];
  float sm = fmaxf(s0, s1);
  float e0 = __expf(s0 - sm), e1 = __expf(s1 - sm);
  float inv = 1.f / (e0 + e1);
  const float SP0 = e0 * inv, SP1 = e1 * inv;

  // ---- A softmax over axis 0: group grp handles column b=grp, l=0,1 ----
  #pragma unroll
  for (int l = 0; l < 2; ++l) {
    float v = lA[a * 256 + grp * 16 + l * 8 + g];
    float m = grpmax16(v);
    float e = __expf(v - m);
    float s = grpsum16(e);
    sA[(l * 16 + grp) * 16 + a] = e / s;
  }
  // ---- Pi softmax over axis 0: groups 0,1 handle l=0,1 ----
  if (grp < 2) {
    float v = lPi[a * 16 + grp * 8 + g];
    float m = grpmax16(v);
    float e = __expf(v - m);
    float s = grpsum16(e);
    sPi[grp * 16 + a] = e / s;
  }
  // ---- B softmax over axis 1 (M): group grp = row c, lane a does m=a+16k ----
  {
    const int c = grp;
    float vv[16];
    float mx = -1e30f;
    #pragma unroll
    for (int k = 0; k < 16; ++k) {
      vv[k] = lB[c * (M_ * G_) + (a + 16 * k) * G_ + g];
      mx = fmaxf(mx, vv[k]);
    }
    mx = grpmax16(mx);
    float ssum = 0.f;
    #pragma unroll
    for (int k = 0; k < 16; ++k) { vv[k] = __expf(vv[k] - mx); ssum += vv[k]; }
    ssum = grpsum16(ssum);
    float is = 1.f / ssum;
    #pragma unroll
    for (int k = 0; k < 16; ++k) sB[(a + 16 * k) * 17 + c] = vv[k] * is;
  }
  __syncthreads();

  // ---- fold SP into per-thread A rows (thread's a is fixed) ----
  float Asp0[16], Asp1[16];
  #pragma unroll
  for (int b = 0; b < 16; ++b) {
    Asp0[b] = sA[(b) * 16 + a] * SP0;          // A[a,b,l=0] * SP[0]
    Asp1[b] = sA[(16 + b) * 16 + a] * SP1;     // A[a,b,l=1] * SP[1]
  }
  const float pi0 = sPi[a], pi1 = sPi[16 + a];

  float llacc = 0.f;

  // ---- leaves: local leaf index il in [0,512), node = base+511+il ----
  for (int il = grp; il < 512; il += 16) {
    int xi = x[base + 511 + il];
    float bv = sB[xi * 17 + a];
    float val = ((il & 1) ? pi1 : pi0) * bv;   // pos = il % 2
    float nu = grpsum16(val);
    bufA[il * 17 + a] = val / nu;
    if (a == 0) llacc += __logf(nu);
  }
  __syncthreads();

  // ---- bottom-up levels: children level k = 9..1 ----
  float* child  = bufA;
  float* parent = bufB;
  for (int k = DEPTH_ - 1; k >= 1; --k) {
    const int U = 1 << (k - 1);        // parents at level k-1
    const int firstPar = U - 1;        // local node index of first parent
    for (int j = grp; j < U; j += 16) {
      const float* bl = child + (2 * j) * 17;     // left child (pos 0)
      const float* br = bl + 17;                  // right child (pos 1)
      float t = 0.f;
      #pragma unroll
      for (int b = 0; b < 16; ++b) t += Asp0[b] * bl[b];
      #pragma unroll
      for (int b = 0; b < 16; ++b) t += Asp1[b] * br[b];
      int xi = x[base + firstPar + j];
      float bu = t * sB[xi * 17 + a];
      float nu = grpsum16(bu);
      parent[j * 17 + a] = bu / nu;
      if (a == 0) llacc += __logf(nu);
    }
    __syncthreads();
    float* tmp = child; child = parent; parent = tmp;
  }

  // ---- block-level reduction of llacc -> out[tree*8+g] ----
  float v = llacc;
  #pragma unroll
  for (int off = 32; off > 0; off >>= 1) v += __shfl_down(v, off, 64);
  if ((tid & 63) == 0) red[tid >> 6] = v;
  __syncthreads();
  if (tid == 0) out[bid] = red[0] + red[1] + red[2] + red[3];
}

extern "C" void kernel_launch(void* const* d_in, const int* in_sizes, int n_in,
                              void* d_out, int out_size, void* d_ws, size_t ws_size,
                              hipStream_t stream) {
  const float* lA  = (const float*)d_in[0];
  const float* lB  = (const float*)d_in[1];
  const float* lPi = (const float*)d_in[2];
  const float* lSP = (const float*)d_in[3];
  const int*   x   = (const int*)d_in[4];
  float* out = (float*)d_out;
  htmm_fwd_kernel<<<dim3(NT_ * G_), dim3(256), 0, stream>>>(lA, lB, lPi, lSP, x, out);
}

// Round 2
// 45.914 us; speedup vs baseline: 1.5645x; 1.5645x over previous
//
#include <hip/hip_runtime.h>

// Bottom-up HTMM forward. One block per (tree, generator); 16 groups of 16
// lanes. Each group evaluates depth-5 subtrees with beliefs entirely in
// registers; 16x16 matvec done via DPP row_ror rotations (VALU pipe), not LDS.
#define G_   8
#define NT_  128
#define NPT_ 1023

typedef float f16v __attribute__((ext_vector_type(16)));

__device__ __forceinline__ float grpmax16(float v) {
  v = fmaxf(v, __shfl_xor(v, 1, 16));
  v = fmaxf(v, __shfl_xor(v, 2, 16));
  v = fmaxf(v, __shfl_xor(v, 4, 16));
  v = fmaxf(v, __shfl_xor(v, 8, 16));
  return v;
}
__device__ __forceinline__ float grpsum16(float v) {
  v += __shfl_xor(v, 1, 16);
  v += __shfl_xor(v, 2, 16);
  v += __shfl_xor(v, 4, 16);
  v += __shfl_xor(v, 8, 16);
  return v;
}

// lane i receives v[(i - R) & 15] within its 16-lane row
template<int R>
__device__ __forceinline__ float rotr16(float v) {
  return __int_as_float(__builtin_amdgcn_update_dpp(
      0, __float_as_int(v), 0x120 | R, 0xF, 0xF, true));
}

template<int R>
__device__ __forceinline__ float dotstep(float v, f16v w, float acc) {
  acc = fmaf(rotr16<R>(v), w[R], acc);
  if constexpr (R < 15) return dotstep<R + 1>(v, w, acc);
  return acc;
}
// t[a] = sum_b W[a][b] * v[b], with w[r] = W[a][(a-r)&15] preloaded per lane
__device__ __forceinline__ float dotrot16(float v, f16v w) {
  return dotstep<1>(v, w, v * w[0]);
}

// Post-order evaluation of a depth-5 subtree. DELTA: depth below subtree root
// (0=root of subtree, 4=leaf). J: index within that depth. Returns this lane's
// belief component; accumulates log(nu) into ll (every lane -> x16, rescaled).
template<int DELTA, int J>
__device__ __forceinline__ float evalN(const float* __restrict__ sB,
                                       f16v w0, f16v w1, float pi0, float pi1,
                                       int a, int leafx, int intx, float& ll) {
  float bu;
  if constexpr (DELTA == 4) {
    int xi = __shfl(leafx, J, 16);
    bu = ((J & 1) ? pi1 : pi0) * sB[xi * 17 + a];
  } else {
    float vL = evalN<DELTA + 1, 2 * J>(sB, w0, w1, pi0, pi1, a, leafx, intx, ll);
    float vR = evalN<DELTA + 1, 2 * J + 1>(sB, w0, w1, pi0, pi1, a, leafx, intx, ll);
    float t = dotrot16(vL, w0) + dotrot16(vR, w1);
    int xi = __shfl(intx, (1 << DELTA) - 1 + J, 16);
    bu = t * sB[xi * 17 + a];
  }
  float nu = grpsum16(bu);
  ll += __logf(nu);
  return bu * __builtin_amdgcn_rcpf(nu);
}

__device__ __forceinline__ void topStep(const float* __restrict__ child,
                                        float* parent, int U, int lvl,
                                        const float* __restrict__ sB,
                                        f16v w0, f16v w1, int a, int grp,
                                        int topx, float& ll) {
  int j = (grp < U) ? grp : 0;            // clamp: keep full-wave EXEC for DPP
  float vL = child[(2 * j) * 17 + a];
  float vR = child[(2 * j + 1) * 17 + a];
  float t = dotrot16(vL, w0) + dotrot16(vR, w1);
  int node = (1 << lvl) - 1 + j;
  int xi = __shfl(topx, node, 64);
  float bu = t * sB[xi * 17 + a];
  float nu = grpsum16(bu);
  if (grp < U) {
    ll += __logf(nu);
    if (parent) parent[grp * 17 + a] = bu * __builtin_amdgcn_rcpf(nu);
  }
  __syncthreads();
}

__global__ __launch_bounds__(256) void htmm_fwd_kernel(
    const float* __restrict__ lA,   // (16,16,2,8)
    const float* __restrict__ lB,   // (16,256,8)
    const float* __restrict__ lPi,  // (16,2,8)
    const float* __restrict__ lSP,  // (2,8)
    const int*   __restrict__ x,    // (128*1023,)
    float*       __restrict__ out)  // (128,8)
{
  __shared__ float sB[256 * 17];    // normalized B, [m][c], stride 17
  __shared__ float sA[2 * 16 * 16]; // normalized A, [l][b][a]
  __shared__ float sPi[32];         // [l][c]
  __shared__ float roots[32 * 17];  // subtree-root beliefs
  __shared__ float topA[16 * 17];
  __shared__ float topB[8 * 17];
  __shared__ float red[4];

  const int tid = threadIdx.x;
  const int bid = blockIdx.x;       // tree*8 + g
  const int T   = bid >> 3;
  const int g   = bid & 7;
  const int a   = tid & 15;
  const int grp = tid >> 4;
  const long base = (long)T * NPT_;

  // ---- SP softmax ----
  float s0 = lSP[g], s1 = lSP[G_ + g];
  float sm = fmaxf(s0, s1);
  float e0 = __expf(s0 - sm), e1 = __expf(s1 - sm);
  float inv = __builtin_amdgcn_rcpf(e0 + e1);
  const float SP0 = e0 * inv, SP1 = e1 * inv;

  // ---- A softmax over axis 0 (lanes = a), column b = grp ----
  #pragma unroll
  for (int l = 0; l < 2; ++l) {
    float v = lA[a * 256 + grp * 16 + l * 8 + g];
    float m = grpmax16(v);
    float e = __expf(v - m);
    float s = grpsum16(e);
    sA[(l * 16 + grp) * 16 + a] = e * __builtin_amdgcn_rcpf(s);
  }
  // ---- Pi softmax over axis 0 ----
  if (grp < 2) {
    float v = lPi[a * 16 + grp * 8 + g];
    float m = grpmax16(v);
    float e = __expf(v - m);
    float s = grpsum16(e);
    sPi[grp * 16 + a] = e * __builtin_amdgcn_rcpf(s);
  }
  // ---- B softmax over axis 1 (M): row c = grp, lane a covers m = a+16k ----
  {
    const int c = grp;
    float vv[16];
    float mx = -1e30f;
    #pragma unroll
    for (int k = 0; k < 16; ++k) {
      vv[k] = lB[c * (256 * G_) + (a + 16 * k) * G_ + g];
      mx = fmaxf(mx, vv[k]);
    }
    mx = grpmax16(mx);
    float ssum = 0.f;
    #pragma unroll
    for (int k = 0; k < 16; ++k) { vv[k] = __expf(vv[k] - mx); ssum += vv[k]; }
    ssum = grpsum16(ssum);
    float is = __builtin_amdgcn_rcpf(ssum);
    #pragma unroll
    for (int k = 0; k < 16; ++k) sB[(a + 16 * k) * 17 + c] = vv[k] * is;
  }
  __syncthreads();

  // ---- per-lane rotated weight vectors: w[r] = A[a][(a-r)&15][l] * SP[l] ----
  f16v w0, w1;
  #pragma unroll
  for (int r = 0; r < 16; ++r) {
    int b = (a - r) & 15;
    w0[r] = sA[b * 16 + a] * SP0;
    w1[r] = sA[(16 + b) * 16 + a] * SP1;
  }
  const float pi0 = sPi[a], pi1 = sPi[16 + a];

  float llacc = 0.f;

  // ---- subtree passes: 32 subtrees, group handles s = grp, grp+16 ----
  for (int pass = 0; pass < 2; ++pass) {
    int s = grp + 16 * pass;
    int leafx = x[base + 511 + 16 * s + a];          // 16 leaf obs, coalesced
    int dpl = 31 - __clz(a + 1);                     // depth of internal node l=a
    int ioff = ((31 + s) << dpl) + a;                // global node index
    int intx = (a < 15) ? x[base + ioff] : 0;        // 15 internal obs
    float r = evalN<0, 0>(sB, w0, w1, pi0, pi1, a, leafx, intx, llacc);
    roots[s * 17 + a] = r;
  }
  __syncthreads();

  // ---- top 31 nodes (levels 4..0) ----
  int tl = tid & 63;
  int topx = x[base + (tl < 31 ? tl : 0)];           // x[0..30] in wave lanes

  topStep(roots, topA, 16, 4, sB, w0, w1, a, grp, topx, llacc);
  topStep(topA, topB, 8, 3, sB, w0, w1, a, grp, topx, llacc);
  topStep(topB, topA, 4, 2, sB, w0, w1, a, grp, topx, llacc);
  topStep(topA, topB, 2, 1, sB, w0, w1, a, grp, topx, llacc);
  topStep(topB, nullptr, 1, 0, sB, w0, w1, a, grp, topx, llacc);

  // ---- block reduce (every lane accumulated log(nu) -> scale by 1/16) ----
  float v = llacc;
  #pragma unroll
  for (int off = 32; off > 0; off >>= 1) v += __shfl_down(v, off, 64);
  if ((tid & 63) == 0) red[tid >> 6] = v;
  __syncthreads();
  if (tid == 0) out[bid] = (red[0] + red[1] + red[2] + red[3]) * 0.0625f;
}

extern "C" void kernel_launch(void* const* d_in, const int* in_sizes, int n_in,
                              void* d_out, int out_size, void* d_ws, size_t ws_size,
                              hipStream_t stream) {
  const float* lA  = (const float*)d_in[0];
  const float* lB  = (const float*)d_in[1];
  const float* lPi = (const float*)d_in[2];
  const float* lSP = (const float*)d_in[3];
  const int*   x   = (const int*)d_in[4];
  float* out = (float*)d_out;
  htmm_fwd_kernel<<<dim3(NT_ * G_), dim3(256), 0, stream>>>(lA, lB, lPi, lSP, x, out);
}

// Round 3
// 42.881 us; speedup vs baseline: 1.6752x; 1.0707x over previous
//
#include <hip/hip_runtime.h>

// Bottom-up HTMM forward. One block per (tree, generator); 16 groups of 16
// lanes. Each group evaluates its two depth-5 subtrees as float2 register
// chains (2x ILP); 16x16 matvec and 16-lane reductions all via DPP row_ror
// on the VALU pipe. Children passed as (raw, rcp(nu)) so the divide hides
// under the next dot product.
#define G_   8
#define NT_  128
#define NPT_ 1023

typedef float f16v __attribute__((ext_vector_type(16)));

// lane i receives v[(i -+ R) & 15] within its 16-lane row (row_ror)
template<int R>
__device__ __forceinline__ float rotr16(float v) {
  return __int_as_float(__builtin_amdgcn_update_dpp(
      0, __float_as_int(v), 0x120 | R, 0xF, 0xF, true));
}

// sum/max broadcast over the 16-lane group: 4 DPP-rotated ops, pure VALU
__device__ __forceinline__ float grpsum16(float v) {
  v += rotr16<8>(v); v += rotr16<4>(v); v += rotr16<2>(v); v += rotr16<1>(v);
  return v;
}
__device__ __forceinline__ float grpmax16(float v) {
  v = fmaxf(v, rotr16<8>(v)); v = fmaxf(v, rotr16<4>(v));
  v = fmaxf(v, rotr16<2>(v)); v = fmaxf(v, rotr16<1>(v));
  return v;
}

// t[a] = sum_b W[a][b]*v[b]; w[r] = W[a][(a-r)&15]. All 15 rotations are
// independent (from original v); FMA chain split into two accumulators.
__device__ __forceinline__ float dotrot16(float v, const f16v& w) {
  float a0 = v * w[0];
  float a1 = rotr16<1>(v) * w[1];
  a0 = fmaf(rotr16<2>(v),  w[2],  a0);
  a1 = fmaf(rotr16<3>(v),  w[3],  a1);
  a0 = fmaf(rotr16<4>(v),  w[4],  a0);
  a1 = fmaf(rotr16<5>(v),  w[5],  a1);
  a0 = fmaf(rotr16<6>(v),  w[6],  a0);
  a1 = fmaf(rotr16<7>(v),  w[7],  a1);
  a0 = fmaf(rotr16<8>(v),  w[8],  a0);
  a1 = fmaf(rotr16<9>(v),  w[9],  a1);
  a0 = fmaf(rotr16<10>(v), w[10], a0);
  a1 = fmaf(rotr16<11>(v), w[11], a1);
  a0 = fmaf(rotr16<12>(v), w[12], a0);
  a1 = fmaf(rotr16<13>(v), w[13], a1);
  a0 = fmaf(rotr16<14>(v), w[14], a0);
  a1 = fmaf(rotr16<15>(v), w[15], a1);
  return a0 + a1;
}

// Post-order evaluation of two depth-5 subtrees at once (float2 lanes .x/.y).
// Returns raw (unnormalized) belief + rcp of its sum; logs nu into ll.
template<int DELTA, int J>
__device__ __forceinline__ void evalN(const float* __restrict__ sB,
                                      const f16v& w0, const f16v& w1,
                                      float pi0, float pi1, int a,
                                      int leafp, int intp,
                                      float2& ll, float2& raw, float2& rcpv) {
  if constexpr (DELTA == 4) {
    int xp = __shfl(leafp, J, 16);
    float pi = (J & 1) ? pi1 : pi0;
    raw.x = pi * sB[(xp & 0xFF) * 17 + a];
    raw.y = pi * sB[(xp >> 16) * 17 + a];
  } else {
    // prefetch this node's B-gather before descending: latency hides under
    // the entire child evaluation
    int xp = __shfl(intp, (1 << DELTA) - 1 + J, 16);
    float bvA = sB[(xp & 0xFF) * 17 + a];
    float bvB = sB[(xp >> 16) * 17 + a];
    float2 rawL, rcpL, rawR, rcpR;
    evalN<DELTA + 1, 2 * J>(sB, w0, w1, pi0, pi1, a, leafp, intp, ll, rawL, rcpL);
    evalN<DELTA + 1, 2 * J + 1>(sB, w0, w1, pi0, pi1, a, leafp, intp, ll, rawR, rcpR);
    float dLx = dotrot16(rawL.x, w0), dLy = dotrot16(rawL.y, w0);
    float dRx = dotrot16(rawR.x, w1), dRy = dotrot16(rawR.y, w1);
    float tx = fmaf(dLx, rcpL.x, dRx * rcpR.x);
    float ty = fmaf(dLy, rcpL.y, dRy * rcpR.y);
    raw.x = tx * bvA;
    raw.y = ty * bvB;
  }
  float nux = grpsum16(raw.x), nuy = grpsum16(raw.y);
  ll.x += __logf(nux);
  ll.y += __logf(nuy);
  rcpv.x = __builtin_amdgcn_rcpf(nux);
  rcpv.y = __builtin_amdgcn_rcpf(nuy);
}

__device__ __forceinline__ void topStep(const float* __restrict__ child,
                                        float* parent, int U, int lvl,
                                        const float* __restrict__ sB,
                                        const f16v& w0, const f16v& w1,
                                        int a, int grp, int topx, float& ll) {
  int j = (grp < U) ? grp : 0;            // clamp: keep full-wave EXEC for DPP
  int node = (1 << lvl) - 1 + j;
  int xi = __shfl(topx, node, 64);
  float bval = sB[xi * 17 + a];
  float vL = child[(2 * j) * 17 + a];
  float vR = child[(2 * j + 1) * 17 + a];
  float t = dotrot16(vL, w0) + dotrot16(vR, w1);
  float bu = t * bval;
  float nu = grpsum16(bu);
  if (grp < U) {
    ll += __logf(nu);
    if (parent) parent[grp * 17 + a] = bu * __builtin_amdgcn_rcpf(nu);
  }
  __syncthreads();
}

__global__ __launch_bounds__(256) void htmm_fwd_kernel(
    const float* __restrict__ lA,   // (16,16,2,8)
    const float* __restrict__ lB,   // (16,256,8)
    const float* __restrict__ lPi,  // (16,2,8)
    const float* __restrict__ lSP,  // (2,8)
    const int*   __restrict__ x,    // (128*1023,)
    float*       __restrict__ out)  // (128,8)
{
  __shared__ float sB[256 * 17];    // normalized B, [m][c], stride 17
  __shared__ float sA[2 * 16 * 16]; // normalized A, [l][b][a]
  __shared__ float sPi[32];         // [l][c]
  __shared__ float roots[32 * 17];  // subtree-root beliefs (normalized)
  __shared__ float topA[16 * 17];
  __shared__ float topB[8 * 17];
  __shared__ float red[4];

  const int tid = threadIdx.x;
  const int bid = blockIdx.x;       // tree*8 + g
  const int T   = bid >> 3;
  const int g   = bid & 7;
  const int a   = tid & 15;
  const int grp = tid >> 4;
  const long base = (long)T * NPT_;

  // ---- SP softmax ----
  float s0 = lSP[g], s1 = lSP[G_ + g];
  float sm = fmaxf(s0, s1);
  float e0 = __expf(s0 - sm), e1 = __expf(s1 - sm);
  float inv = __builtin_amdgcn_rcpf(e0 + e1);
  const float SP0 = e0 * inv, SP1 = e1 * inv;

  // ---- A softmax over axis 0 (lanes = a), column b = grp ----
  #pragma unroll
  for (int l = 0; l < 2; ++l) {
    float v = lA[a * 256 + grp * 16 + l * 8 + g];
    float m = grpmax16(v);
    float e = __expf(v - m);
    float s = grpsum16(e);
    sA[(l * 16 + grp) * 16 + a] = e * __builtin_amdgcn_rcpf(s);
  }
  // ---- Pi softmax over axis 0 ----
  if (grp < 2) {
    float v = lPi[a * 16 + grp * 8 + g];
    float m = grpmax16(v);
    float e = __expf(v - m);
    float s = grpsum16(e);
    sPi[grp * 16 + a] = e * __builtin_amdgcn_rcpf(s);
  }
  // ---- B softmax over axis 1 (M): row c = grp, lane a covers m = a+16k ----
  {
    const int c = grp;
    float vv[16];
    float mx = -1e30f;
    #pragma unroll
    for (int k = 0; k < 16; ++k) {
      vv[k] = lB[c * (256 * G_) + (a + 16 * k) * G_ + g];
      mx = fmaxf(mx, vv[k]);
    }
    mx = grpmax16(mx);
    float ssum = 0.f;
    #pragma unroll
    for (int k = 0; k < 16; ++k) { vv[k] = __expf(vv[k] - mx); ssum += vv[k]; }
    ssum = grpsum16(ssum);
    float is = __builtin_amdgcn_rcpf(ssum);
    #pragma unroll
    for (int k = 0; k < 16; ++k) sB[(a + 16 * k) * 17 + c] = vv[k] * is;
  }
  __syncthreads();

  // ---- per-lane rotated weight vectors: w[r] = A[a][(a-r)&15][l] * SP[l] ----
  f16v w0, w1;
  #pragma unroll
  for (int r = 0; r < 16; ++r) {
    int b = (a - r) & 15;
    w0[r] = sA[b * 16 + a] * SP0;
    w1[r] = sA[(16 + b) * 16 + a] * SP1;
  }
  const float pi0 = sPi[a], pi1 = sPi[16 + a];

  // ---- observation indices for this group's two subtrees (packed, x<256) --
  int lxA = x[base + 511 + 16 * grp + a];
  int lxB = x[base + 511 + 16 * (grp + 16) + a];
  int leafp = lxA | (lxB << 16);
  int dpl = 31 - __clz(a + 1);
  int iA = (a < 15) ? x[base + ((31 + grp) << dpl) + a] : 0;
  int iB = (a < 15) ? x[base + ((31 + grp + 16) << dpl) + a] : 0;
  int intp = iA | (iB << 16);

  float2 ll = {0.f, 0.f};
  float2 rraw, rrcp;
  evalN<0, 0>(sB, w0, w1, pi0, pi1, a, leafp, intp, ll, rraw, rrcp);
  roots[grp * 17 + a]        = rraw.x * rrcp.x;
  roots[(grp + 16) * 17 + a] = rraw.y * rrcp.y;
  __syncthreads();

  // ---- top 31 nodes (levels 4..0) ----
  float llt = 0.f;
  int tl = tid & 63;
  int topx = x[base + (tl < 31 ? tl : 0)];           // x[0..30] in wave lanes

  topStep(roots, topA, 16, 4, sB, w0, w1, a, grp, topx, llt);
  topStep(topA, topB, 8, 3, sB, w0, w1, a, grp, topx, llt);
  topStep(topB, topA, 4, 2, sB, w0, w1, a, grp, topx, llt);
  topStep(topA, topB, 2, 1, sB, w0, w1, a, grp, topx, llt);
  topStep(topB, nullptr, 1, 0, sB, w0, w1, a, grp, topx, llt);

  // ---- block reduce (every lane of a group logged nu -> scale by 1/16) ----
  float v = ll.x + ll.y + llt;
  #pragma unroll
  for (int off = 32; off > 0; off >>= 1) v += __shfl_down(v, off, 64);
  if ((tid & 63) == 0) red[tid >> 6] = v;
  __syncthreads();
  if (tid == 0) out[bid] = (red[0] + red[1] + red[2] + red[3]) * 0.0625f;
}

extern "C" void kernel_launch(void* const* d_in, const int* in_sizes, int n_in,
                              void* d_out, int out_size, void* d_ws, size_t ws_size,
                              hipStream_t stream) {
  const float* lA  = (const float*)d_in[0];
  const float* lB  = (const float*)d_in[1];
  const float* lPi = (const float*)d_in[2];
  const float* lSP = (const float*)d_in[3];
  const int*   x   = (const int*)d_in[4];
  float* out = (float*)d_out;
  htmm_fwd_kernel<<<dim3(NT_ * G_), dim3(256), 0, stream>>>(lA, lB, lPi, lSP, x, out);
}

// Round 4
// 38.404 us; speedup vs baseline: 1.8705x; 1.1166x over previous
//
#include <hip/hip_runtime.h>

// Bottom-up HTMM forward. One block per (tree, generator); 16 groups of 16
// lanes. Each group evaluates its two depth-5 subtrees as float2 register
// chains; 16x16 matvec done with hand-fused v_fmac_f32_dpp (row_ror) and
// 16-lane reductions with v_add_f32_dpp — pure VALU pipe, no mov_dpp bloat.
#define G_   8
#define NT_  128
#define NPT_ 1023

typedef float f16v __attribute__((ext_vector_type(16)));

// lane i receives v[(i - R) & 15] within its 16-lane row (row_ror)
template<int R>
__device__ __forceinline__ float rotr16(float v) {
  return __int_as_float(__builtin_amdgcn_update_dpp(
      0, __float_as_int(v), 0x120 | R, 0xF, 0xF, true));
}
// builtin-path reduces (compiler handles DPP hazards) — cold paths only
__device__ __forceinline__ float grpsum16(float v) {
  v += rotr16<8>(v); v += rotr16<4>(v); v += rotr16<2>(v); v += rotr16<1>(v);
  return v;
}
__device__ __forceinline__ float grpmax16(float v) {
  v = fmaxf(v, rotr16<8>(v)); v = fmaxf(v, rotr16<4>(v));
  v = fmaxf(v, rotr16<2>(v)); v = fmaxf(v, rotr16<1>(v));
  return v;
}
// builtin-path dot (cold top phase)
__device__ __forceinline__ float dotrot16(float v, const f16v& w) {
  float a0 = v * w[0];
  float a1 = rotr16<1>(v) * w[1];
  a0 = fmaf(rotr16<2>(v),  w[2],  a0);
  a1 = fmaf(rotr16<3>(v),  w[3],  a1);
  a0 = fmaf(rotr16<4>(v),  w[4],  a0);
  a1 = fmaf(rotr16<5>(v),  w[5],  a1);
  a0 = fmaf(rotr16<6>(v),  w[6],  a0);
  a1 = fmaf(rotr16<7>(v),  w[7],  a1);
  a0 = fmaf(rotr16<8>(v),  w[8],  a0);
  a1 = fmaf(rotr16<9>(v),  w[9],  a1);
  a0 = fmaf(rotr16<10>(v), w[10], a0);
  a1 = fmaf(rotr16<11>(v), w[11], a1);
  a0 = fmaf(rotr16<12>(v), w[12], a0);
  a1 = fmaf(rotr16<13>(v), w[13], a1);
  a0 = fmaf(rotr16<14>(v), w[14], a0);
  a1 = fmaf(rotr16<15>(v), w[15], a1);
  return a0 + a1;
}

// ---- hot path: 4 dots (L/R children x float2) with fused v_fmac_f32_dpp.
// Round-robin over 4 accumulators: self-dep distance 4 instrs >= FMA latency;
// DPP sources (vL*/vR*) written well before (s_nop 1 guards block entry).
#define FMAC4_R(R) \
  asm("v_fmac_f32_dpp %0, %4, %8 row_ror:" #R " row_mask:0xf bank_mask:0xf\n\t" \
      "v_fmac_f32_dpp %1, %5, %8 row_ror:" #R " row_mask:0xf bank_mask:0xf\n\t" \
      "v_fmac_f32_dpp %2, %6, %9 row_ror:" #R " row_mask:0xf bank_mask:0xf\n\t" \
      "v_fmac_f32_dpp %3, %7, %9 row_ror:" #R " row_mask:0xf bank_mask:0xf"     \
      : "+v"(aLx), "+v"(aLy), "+v"(aRx), "+v"(aRy)                              \
      : "v"(vLx), "v"(vLy), "v"(vRx), "v"(vRy), "v"(w0[R]), "v"(w1[R]))
#define FMAC4_FIRST(R) \
  asm("s_nop 1\n\t"                                                             \
      "v_fmac_f32_dpp %0, %4, %8 row_ror:" #R " row_mask:0xf bank_mask:0xf\n\t" \
      "v_fmac_f32_dpp %1, %5, %8 row_ror:" #R " row_mask:0xf bank_mask:0xf\n\t" \
      "v_fmac_f32_dpp %2, %6, %9 row_ror:" #R " row_mask:0xf bank_mask:0xf\n\t" \
      "v_fmac_f32_dpp %3, %7, %9 row_ror:" #R " row_mask:0xf bank_mask:0xf"     \
      : "+v"(aLx), "+v"(aLy), "+v"(aRx), "+v"(aRy)                              \
      : "v"(vLx), "v"(vLy), "v"(vRx), "v"(vRy), "v"(w0[R]), "v"(w1[R]))

__device__ __forceinline__ void dot4(float vLx, float vLy, float vRx, float vRy,
                                     const f16v& w0, const f16v& w1,
                                     float& oLx, float& oLy, float& oRx, float& oRy) {
  float aLx = vLx * w0[0];
  float aLy = vLy * w0[0];
  float aRx = vRx * w1[0];
  float aRy = vRy * w1[0];
  FMAC4_FIRST(1);
  FMAC4_R(2);  FMAC4_R(3);  FMAC4_R(4);  FMAC4_R(5);
  FMAC4_R(6);  FMAC4_R(7);  FMAC4_R(8);  FMAC4_R(9);
  FMAC4_R(10); FMAC4_R(11); FMAC4_R(12); FMAC4_R(13);
  FMAC4_R(14); FMAC4_R(15);
  oLx = aLx; oLy = aLy; oRx = aRx; oRy = aRy;
}

// dual non-destructive 16-lane sum via v_add_f32_dpp; s_nops cover the
// VALU-write -> DPP-read hazard (2 wait states) the compiler can't see.
__device__ __forceinline__ void grpsum2(float rx, float ry, float& nux, float& nuy) {
  asm("s_nop 1\n\t"
      "v_add_f32_dpp %0, %2, %2 row_ror:8 row_mask:0xf bank_mask:0xf\n\t"
      "v_add_f32_dpp %1, %3, %3 row_ror:8 row_mask:0xf bank_mask:0xf\n\t"
      "s_nop 0\n\t"
      "v_add_f32_dpp %0, %0, %0 row_ror:4 row_mask:0xf bank_mask:0xf\n\t"
      "v_add_f32_dpp %1, %1, %1 row_ror:4 row_mask:0xf bank_mask:0xf\n\t"
      "s_nop 0\n\t"
      "v_add_f32_dpp %0, %0, %0 row_ror:2 row_mask:0xf bank_mask:0xf\n\t"
      "v_add_f32_dpp %1, %1, %1 row_ror:2 row_mask:0xf bank_mask:0xf\n\t"
      "s_nop 0\n\t"
      "v_add_f32_dpp %0, %0, %0 row_ror:1 row_mask:0xf bank_mask:0xf\n\t"
      "v_add_f32_dpp %1, %1, %1 row_ror:1 row_mask:0xf bank_mask:0xf"
      : "=&v"(nux), "=&v"(nuy)
      : "v"(rx), "v"(ry));
}

// Post-order evaluation of two depth-5 subtrees at once (float2 lanes .x/.y).
// Packed indices carry x*17 (pre-scaled LDS row offset). sBa = sB + lane_a.
template<int DELTA, int J>
__device__ __forceinline__ void evalN(const float* __restrict__ sBa,
                                      const f16v& w0, const f16v& w1,
                                      float pi0, float pi1,
                                      int leafp, int intp,
                                      float2& ll, float2& raw, float2& rcpv) {
  if constexpr (DELTA == 4) {
    int xp = __shfl(leafp, J, 16);
    float pi = (J & 1) ? pi1 : pi0;
    raw.x = pi * sBa[xp & 0xFFFF];
    raw.y = pi * sBa[((unsigned)xp) >> 16];
  } else {
    // prefetch this node's B-gather before descending (hides LDS latency)
    int xp = __shfl(intp, (1 << DELTA) - 1 + J, 16);
    float bvA = sBa[xp & 0xFFFF];
    float bvB = sBa[((unsigned)xp) >> 16];
    float2 rawL, rcpL, rawR, rcpR;
    evalN<DELTA + 1, 2 * J>(sBa, w0, w1, pi0, pi1, leafp, intp, ll, rawL, rcpL);
    evalN<DELTA + 1, 2 * J + 1>(sBa, w0, w1, pi0, pi1, leafp, intp, ll, rawR, rcpR);
    float dLx, dLy, dRx, dRy;
    dot4(rawL.x, rawL.y, rawR.x, rawR.y, w0, w1, dLx, dLy, dRx, dRy);
    float tx = fmaf(dLx, rcpL.x, dRx * rcpR.x);
    float ty = fmaf(dLy, rcpL.y, dRy * rcpR.y);
    raw.x = tx * bvA;
    raw.y = ty * bvB;
  }
  float nux, nuy;
  grpsum2(raw.x, raw.y, nux, nuy);
  ll.x += __logf(nux);
  ll.y += __logf(nuy);
  rcpv.x = __builtin_amdgcn_rcpf(nux);
  rcpv.y = __builtin_amdgcn_rcpf(nuy);
}

__device__ __forceinline__ void topStep(const float* __restrict__ child,
                                        float* parent, int U, int lvl,
                                        const float* __restrict__ sB,
                                        const f16v& w0, const f16v& w1,
                                        int a, int grp, int topx, float& ll) {
  int j = (grp < U) ? grp : 0;            // clamp: keep full-wave EXEC for DPP
  int node = (1 << lvl) - 1 + j;
  int xi = __shfl(topx, node, 64);
  float bval = sB[xi * 17 + a];
  float vL = child[(2 * j) * 17 + a];
  float vR = child[(2 * j + 1) * 17 + a];
  float t = dotrot16(vL, w0) + dotrot16(vR, w1);
  float bu = t * bval;
  float nu = grpsum16(bu);
  if (grp < U) {
    ll += __logf(nu);
    if (parent) parent[grp * 17 + a] = bu * __builtin_amdgcn_rcpf(nu);
  }
  __syncthreads();
}

__global__ __launch_bounds__(256) void htmm_fwd_kernel(
    const float* __restrict__ lA,   // (16,16,2,8)
    const float* __restrict__ lB,   // (16,256,8)
    const float* __restrict__ lPi,  // (16,2,8)
    const float* __restrict__ lSP,  // (2,8)
    const int*   __restrict__ x,    // (128*1023,)
    float*       __restrict__ out)  // (128,8)
{
  __shared__ float sB[256 * 17];    // normalized B, [m][c], stride 17
  __shared__ float sA[2 * 16 * 16]; // normalized A, [l][b][a]
  __shared__ float sPi[32];         // [l][c]
  __shared__ float roots[32 * 17];  // subtree-root beliefs (normalized)
  __shared__ float topA[16 * 17];
  __shared__ float topB[8 * 17];
  __shared__ float red[4];

  const int tid = threadIdx.x;
  const int bid = blockIdx.x;       // tree*8 + g
  const int T   = bid >> 3;
  const int g   = bid & 7;
  const int a   = tid & 15;
  const int grp = tid >> 4;
  const long base = (long)T * NPT_;

  // ---- SP softmax ----
  float s0 = lSP[g], s1 = lSP[G_ + g];
  float sm = fmaxf(s0, s1);
  float e0 = __expf(s0 - sm), e1 = __expf(s1 - sm);
  float inv = __builtin_amdgcn_rcpf(e0 + e1);
  const float SP0 = e0 * inv, SP1 = e1 * inv;

  // ---- A softmax over axis 0 (lanes = a), column b = grp ----
  #pragma unroll
  for (int l = 0; l < 2; ++l) {
    float v = lA[a * 256 + grp * 16 + l * 8 + g];
    float m = grpmax16(v);
    float e = __expf(v - m);
    float s = grpsum16(e);
    sA[(l * 16 + grp) * 16 + a] = e * __builtin_amdgcn_rcpf(s);
  }
  // ---- Pi softmax over axis 0 ----
  if (grp < 2) {
    float v = lPi[a * 16 + grp * 8 + g];
    float m = grpmax16(v);
    float e = __expf(v - m);
    float s = grpsum16(e);
    sPi[grp * 16 + a] = e * __builtin_amdgcn_rcpf(s);
  }
  // ---- B softmax over axis 1 (M): row c = grp, lane a covers m = a+16k ----
  {
    const int c = grp;
    float vv[16];
    float mx = -1e30f;
    #pragma unroll
    for (int k = 0; k < 16; ++k) {
      vv[k] = lB[c * (256 * G_) + (a + 16 * k) * G_ + g];
      mx = fmaxf(mx, vv[k]);
    }
    mx = grpmax16(mx);
    float ssum = 0.f;
    #pragma unroll
    for (int k = 0; k < 16; ++k) { vv[k] = __expf(vv[k] - mx); ssum += vv[k]; }
    ssum = grpsum16(ssum);
    float is = __builtin_amdgcn_rcpf(ssum);
    #pragma unroll
    for (int k = 0; k < 16; ++k) sB[(a + 16 * k) * 17 + c] = vv[k] * is;
  }
  __syncthreads();

  // ---- per-lane rotated weight vectors: w[r] = A[a][(a-r)&15][l] * SP[l] ----
  f16v w0, w1;
  #pragma unroll
  for (int r = 0; r < 16; ++r) {
    int b = (a - r) & 15;
    w0[r] = sA[b * 16 + a] * SP0;
    w1[r] = sA[(16 + b) * 16 + a] * SP1;
  }
  const float pi0 = sPi[a], pi1 = sPi[16 + a];
  const float* sBa = sB + a;

  // ---- observation indices, pre-scaled by 17 and packed (x<256 => <16b) ----
  int lxA = x[base + 511 + 16 * grp + a] * 17;
  int lxB = x[base + 511 + 16 * (grp + 16) + a] * 17;
  int leafp = lxA | (lxB << 16);
  int dpl = 31 - __clz(a + 1);
  int iA = (a < 15) ? x[base + ((31 + grp) << dpl) + a] * 17 : 0;
  int iB = (a < 15) ? x[base + ((31 + grp + 16) << dpl) + a] * 17 : 0;
  int intp = iA | (iB << 16);

  float2 ll = {0.f, 0.f};
  float2 rraw, rrcp;
  evalN<0, 0>(sBa, w0, w1, pi0, pi1, leafp, intp, ll, rraw, rrcp);
  roots[grp * 17 + a]        = rraw.x * rrcp.x;
  roots[(grp + 16) * 17 + a] = rraw.y * rrcp.y;
  __syncthreads();

  // ---- top 31 nodes (levels 4..0) ----
  float llt = 0.f;
  int tl = tid & 63;
  int topx = x[base + (tl < 31 ? tl : 0)];           // x[0..30] in wave lanes

  topStep(roots, topA, 16, 4, sB, w0, w1, a, grp, topx, llt);
  topStep(topA, topB, 8, 3, sB, w0, w1, a, grp, topx, llt);
  topStep(topB, topA, 4, 2, sB, w0, w1, a, grp, topx, llt);
  topStep(topA, topB, 2, 1, sB, w0, w1, a, grp, topx, llt);
  topStep(topB, nullptr, 1, 0, sB, w0, w1, a, grp, topx, llt);

  // ---- block reduce (every lane of a group logged nu -> scale by 1/16) ----
  float v = ll.x + ll.y + llt;
  #pragma unroll
  for (int off = 32; off > 0; off >>= 1) v += __shfl_down(v, off, 64);
  if ((tid & 63) == 0) red[tid >> 6] = v;
  __syncthreads();
  if (tid == 0) out[bid] = (red[0] + red[1] + red[2] + red[3]) * 0.0625f;
}

extern "C" void kernel_launch(void* const* d_in, const int* in_sizes, int n_in,
                              void* d_out, int out_size, void* d_ws, size_t ws_size,
                              hipStream_t stream) {
  const float* lA  = (const float*)d_in[0];
  const float* lB  = (const float*)d_in[1];
  const float* lPi = (const float*)d_in[2];
  const float* lSP = (const float*)d_in[3];
  const int*   x   = (const int*)d_in[4];
  float* out = (float*)d_out;
  htmm_fwd_kernel<<<dim3(NT_ * G_), dim3(256), 0, stream>>>(lA, lB, lPi, lSP, x, out);
}

// Round 5
// 29.117 us; speedup vs baseline: 2.4671x; 1.3190x over previous
//
#include <hip/hip_runtime.h>

// Bottom-up HTMM forward. One block per (tree, generator); 16 groups of 16
// lanes. Each group evaluates its two depth-5 subtrees as float2 register
// chains; 16x16 matvec with hand-fused v_fmac_f32_dpp (row_ror); 16-lane
// reductions with v_add_f32_dpp. Leaf gathers hoisted+pipelined at chain
// start; log accumulated in log2 and scaled once at the end.
#define G_   8
#define NT_  128
#define NPT_ 1023

typedef float f16v __attribute__((ext_vector_type(16)));

// lane i receives v[(i - R) & 15] within its 16-lane row (row_ror)
template<int R>
__device__ __forceinline__ float rotr16(float v) {
  return __int_as_float(__builtin_amdgcn_update_dpp(
      0, __float_as_int(v), 0x120 | R, 0xF, 0xF, true));
}
// builtin-path reduces (compiler handles DPP hazards) — cold paths only
__device__ __forceinline__ float grpsum16(float v) {
  v += rotr16<8>(v); v += rotr16<4>(v); v += rotr16<2>(v); v += rotr16<1>(v);
  return v;
}
__device__ __forceinline__ float grpmax16(float v) {
  v = fmaxf(v, rotr16<8>(v)); v = fmaxf(v, rotr16<4>(v));
  v = fmaxf(v, rotr16<2>(v)); v = fmaxf(v, rotr16<1>(v));
  return v;
}
// builtin-path dot (cold top phase)
__device__ __forceinline__ float dotrot16(float v, const f16v& w) {
  float a0 = v * w[0];
  float a1 = rotr16<1>(v) * w[1];
  a0 = fmaf(rotr16<2>(v),  w[2],  a0);
  a1 = fmaf(rotr16<3>(v),  w[3],  a1);
  a0 = fmaf(rotr16<4>(v),  w[4],  a0);
  a1 = fmaf(rotr16<5>(v),  w[5],  a1);
  a0 = fmaf(rotr16<6>(v),  w[6],  a0);
  a1 = fmaf(rotr16<7>(v),  w[7],  a1);
  a0 = fmaf(rotr16<8>(v),  w[8],  a0);
  a1 = fmaf(rotr16<9>(v),  w[9],  a1);
  a0 = fmaf(rotr16<10>(v), w[10], a0);
  a1 = fmaf(rotr16<11>(v), w[11], a1);
  a0 = fmaf(rotr16<12>(v), w[12], a0);
  a1 = fmaf(rotr16<13>(v), w[13], a1);
  a0 = fmaf(rotr16<14>(v), w[14], a0);
  a1 = fmaf(rotr16<15>(v), w[15], a1);
  return a0 + a1;
}

// ---- hot path: 4 dots (L/R children x float2) with fused v_fmac_f32_dpp.
// Round-robin over 4 accumulators: self-dep distance 4 >= FMA latency; DPP
// source operands written well before (s_nop 1 guards block entry).
#define FMAC4_R(R) \
  asm("v_fmac_f32_dpp %0, %4, %8 row_ror:" #R " row_mask:0xf bank_mask:0xf\n\t" \
      "v_fmac_f32_dpp %1, %5, %8 row_ror:" #R " row_mask:0xf bank_mask:0xf\n\t" \
      "v_fmac_f32_dpp %2, %6, %9 row_ror:" #R " row_mask:0xf bank_mask:0xf\n\t" \
      "v_fmac_f32_dpp %3, %7, %9 row_ror:" #R " row_mask:0xf bank_mask:0xf"     \
      : "+v"(aLx), "+v"(aLy), "+v"(aRx), "+v"(aRy)                              \
      : "v"(vLx), "v"(vLy), "v"(vRx), "v"(vRy), "v"(w0[R]), "v"(w1[R]))
#define FMAC4_FIRST(R) \
  asm("s_nop 1\n\t"                                                             \
      "v_fmac_f32_dpp %0, %4, %8 row_ror:" #R " row_mask:0xf bank_mask:0xf\n\t" \
      "v_fmac_f32_dpp %1, %5, %8 row_ror:" #R " row_mask:0xf bank_mask:0xf\n\t" \
      "v_fmac_f32_dpp %2, %6, %9 row_ror:" #R " row_mask:0xf bank_mask:0xf\n\t" \
      "v_fmac_f32_dpp %3, %7, %9 row_ror:" #R " row_mask:0xf bank_mask:0xf"     \
      : "+v"(aLx), "+v"(aLy), "+v"(aRx), "+v"(aRy)                              \
      : "v"(vLx), "v"(vLy), "v"(vRx), "v"(vRy), "v"(w0[R]), "v"(w1[R]))

__device__ __forceinline__ void dot4(float vLx, float vLy, float vRx, float vRy,
                                     const f16v& w0, const f16v& w1,
                                     float& oLx, float& oLy, float& oRx, float& oRy) {
  float aLx = vLx * w0[0];
  float aLy = vLy * w0[0];
  float aRx = vRx * w1[0];
  float aRy = vRy * w1[0];
  FMAC4_FIRST(1);
  FMAC4_R(2);  FMAC4_R(3);  FMAC4_R(4);  FMAC4_R(5);
  FMAC4_R(6);  FMAC4_R(7);  FMAC4_R(8);  FMAC4_R(9);
  FMAC4_R(10); FMAC4_R(11); FMAC4_R(12); FMAC4_R(13);
  FMAC4_R(14); FMAC4_R(15);
  oLx = aLx; oLy = aLy; oRx = aRx; oRy = aRy;
}

// dual non-destructive 16-lane sum via v_add_f32_dpp; s_nops cover the
// same-reg VALU-write -> DPP-read hazard the compiler can't see.
__device__ __forceinline__ void grpsum2(float rx, float ry, float& nux, float& nuy) {
  asm("s_nop 1\n\t"
      "v_add_f32_dpp %0, %2, %2 row_ror:8 row_mask:0xf bank_mask:0xf\n\t"
      "v_add_f32_dpp %1, %3, %3 row_ror:8 row_mask:0xf bank_mask:0xf\n\t"
      "s_nop 0\n\t"
      "v_add_f32_dpp %0, %0, %0 row_ror:4 row_mask:0xf bank_mask:0xf\n\t"
      "v_add_f32_dpp %1, %1, %1 row_ror:4 row_mask:0xf bank_mask:0xf\n\t"
      "s_nop 0\n\t"
      "v_add_f32_dpp %0, %0, %0 row_ror:2 row_mask:0xf bank_mask:0xf\n\t"
      "v_add_f32_dpp %1, %1, %1 row_ror:2 row_mask:0xf bank_mask:0xf\n\t"
      "s_nop 0\n\t"
      "v_add_f32_dpp %0, %0, %0 row_ror:1 row_mask:0xf bank_mask:0xf\n\t"
      "v_add_f32_dpp %1, %1, %1 row_ror:1 row_mask:0xf bank_mask:0xf"
      : "=&v"(nux), "=&v"(nuy)
      : "v"(rx), "v"(ry));
}

// quad 16-lane sum: 4 interleaved DPP chains, round-robin distance 4 -> no
// nops needed (inputs are long-lived leaf registers).
__device__ __forceinline__ void grpsum4(float r0, float r1, float r2, float r3,
                                        float& n0, float& n1, float& n2, float& n3) {
  asm("v_add_f32_dpp %0, %4, %4 row_ror:8 row_mask:0xf bank_mask:0xf\n\t"
      "v_add_f32_dpp %1, %5, %5 row_ror:8 row_mask:0xf bank_mask:0xf\n\t"
      "v_add_f32_dpp %2, %6, %6 row_ror:8 row_mask:0xf bank_mask:0xf\n\t"
      "v_add_f32_dpp %3, %7, %7 row_ror:8 row_mask:0xf bank_mask:0xf\n\t"
      "v_add_f32_dpp %0, %0, %0 row_ror:4 row_mask:0xf bank_mask:0xf\n\t"
      "v_add_f32_dpp %1, %1, %1 row_ror:4 row_mask:0xf bank_mask:0xf\n\t"
      "v_add_f32_dpp %2, %2, %2 row_ror:4 row_mask:0xf bank_mask:0xf\n\t"
      "v_add_f32_dpp %3, %3, %3 row_ror:4 row_mask:0xf bank_mask:0xf\n\t"
      "v_add_f32_dpp %0, %0, %0 row_ror:2 row_mask:0xf bank_mask:0xf\n\t"
      "v_add_f32_dpp %1, %1, %1 row_ror:2 row_mask:0xf bank_mask:0xf\n\t"
      "v_add_f32_dpp %2, %2, %2 row_ror:2 row_mask:0xf bank_mask:0xf\n\t"
      "v_add_f32_dpp %3, %3, %3 row_ror:2 row_mask:0xf bank_mask:0xf\n\t"
      "v_add_f32_dpp %0, %0, %0 row_ror:1 row_mask:0xf bank_mask:0xf\n\t"
      "v_add_f32_dpp %1, %1, %1 row_ror:1 row_mask:0xf bank_mask:0xf\n\t"
      "v_add_f32_dpp %2, %2, %2 row_ror:1 row_mask:0xf bank_mask:0xf\n\t"
      "v_add_f32_dpp %3, %3, %3 row_ror:1 row_mask:0xf bank_mask:0xf"
      : "=&v"(n0), "=&v"(n1), "=&v"(n2), "=&v"(n3)
      : "v"(r0), "v"(r1), "v"(r2), "v"(r3));
}

// Post-order evaluation of two depth-5 subtrees at once (float2 lanes .x/.y).
// DELTA 0..3; leaves (DELTA 4) are pre-gathered registers consumed at DELTA 3.
// intp packs x*17 for the 15 internal nodes (lane = heap index). Accumulates
// log2(nu); caller scales by ln2/16 at the end.
template<int DELTA, int J>
__device__ __forceinline__ void evalN(const float* __restrict__ sBa,
                                      const f16v& w0, const f16v& w1,
                                      const f16v& lfx, const f16v& lfy,
                                      int intp,
                                      float2& ll, float2& raw, float2& rcpv) {
  // prefetch this node's B-gather before descending (hides LDS latency)
  int xp = __shfl(intp, (1 << DELTA) - 1 + J, 16);
  float bvA = sBa[xp & 0xFFFF];
  float bvB = sBa[((unsigned)xp) >> 16];
  float2 rawL, rcpL, rawR, rcpR;
  if constexpr (DELTA == 3) {
    // leaves 2J, 2J+1 from hoisted registers; one 4-wide reduce
    float rLx = lfx[2 * J],     rLy = lfy[2 * J];
    float rRx = lfx[2 * J + 1], rRy = lfy[2 * J + 1];
    float nLx, nLy, nRx, nRy;
    grpsum4(rLx, rLy, rRx, rRy, nLx, nLy, nRx, nRy);
    ll.x += __log2f(nLx) + __log2f(nRx);
    ll.y += __log2f(nLy) + __log2f(nRy);
    rawL.x = rLx; rawL.y = rLy; rawR.x = rRx; rawR.y = rRy;
    rcpL.x = __builtin_amdgcn_rcpf(nLx);
    rcpL.y = __builtin_amdgcn_rcpf(nLy);
    rcpR.x = __builtin_amdgcn_rcpf(nRx);
    rcpR.y = __builtin_amdgcn_rcpf(nRy);
  } else {
    evalN<DELTA + 1, 2 * J>(sBa, w0, w1, lfx, lfy, intp, ll, rawL, rcpL);
    evalN<DELTA + 1, 2 * J + 1>(sBa, w0, w1, lfx, lfy, intp, ll, rawR, rcpR);
  }
  float dLx, dLy, dRx, dRy;
  dot4(rawL.x, rawL.y, rawR.x, rawR.y, w0, w1, dLx, dLy, dRx, dRy);
  float tx = fmaf(dLx, rcpL.x, dRx * rcpR.x);
  float ty = fmaf(dLy, rcpL.y, dRy * rcpR.y);
  raw.x = tx * bvA;
  raw.y = ty * bvB;
  float nux, nuy;
  grpsum2(raw.x, raw.y, nux, nuy);
  ll.x += __log2f(nux);
  ll.y += __log2f(nuy);
  rcpv.x = __builtin_amdgcn_rcpf(nux);
  rcpv.y = __builtin_amdgcn_rcpf(nuy);
}

__device__ __forceinline__ void topStep(const float* __restrict__ child,
                                        float* parent, int U, int lvl,
                                        const float* __restrict__ sB,
                                        const f16v& w0, const f16v& w1,
                                        int a, int grp, int topx, float& ll) {
  int j = (grp < U) ? grp : 0;            // clamp: keep full-wave EXEC for DPP
  int node = (1 << lvl) - 1 + j;
  int xi = __shfl(topx, node, 64);
  float bval = sB[xi * 17 + a];
  float vL = child[(2 * j) * 17 + a];
  float vR = child[(2 * j + 1) * 17 + a];
  float t = dotrot16(vL, w0) + dotrot16(vR, w1);
  float bu = t * bval;
  float nu = grpsum16(bu);
  if (grp < U) {
    ll += __log2f(nu);
    if (parent) parent[grp * 17 + a] = bu * __builtin_amdgcn_rcpf(nu);
  }
  __syncthreads();
}

__global__ __launch_bounds__(256, 4) void htmm_fwd_kernel(
    const float* __restrict__ lA,   // (16,16,2,8)
    const float* __restrict__ lB,   // (16,256,8)
    const float* __restrict__ lPi,  // (16,2,8)
    const float* __restrict__ lSP,  // (2,8)
    const int*   __restrict__ x,    // (128*1023,)
    float*       __restrict__ out)  // (128,8)
{
  __shared__ float sB[256 * 17];    // normalized B, [m][c], stride 17
  __shared__ float sA[2 * 16 * 16]; // normalized A, [l][b][a]
  __shared__ float sPi[32];         // [l][c]
  __shared__ float roots[32 * 17];  // subtree-root beliefs (normalized)
  __shared__ float topA[16 * 17];
  __shared__ float topB[8 * 17];
  __shared__ float red[4];

  const int tid = threadIdx.x;
  const int bid = blockIdx.x;       // tree*8 + g
  const int T   = bid >> 3;
  const int g   = bid & 7;
  const int a   = tid & 15;
  const int grp = tid >> 4;
  const long base = (long)T * NPT_;

  // ---- SP softmax ----
  float s0 = lSP[g], s1 = lSP[G_ + g];
  float sm = fmaxf(s0, s1);
  float e0 = __expf(s0 - sm), e1 = __expf(s1 - sm);
  float inv = __builtin_amdgcn_rcpf(e0 + e1);
  const float SP0 = e0 * inv, SP1 = e1 * inv;

  // ---- A softmax over axis 0 (lanes = a), column b = grp ----
  #pragma unroll
  for (int l = 0; l < 2; ++l) {
    float v = lA[a * 256 + grp * 16 + l * 8 + g];
    float m = grpmax16(v);
    float e = __expf(v - m);
    float s = grpsum16(e);
    sA[(l * 16 + grp) * 16 + a] = e * __builtin_amdgcn_rcpf(s);
  }
  // ---- Pi softmax over axis 0 ----
  if (grp < 2) {
    float v = lPi[a * 16 + grp * 8 + g];
    float m = grpmax16(v);
    float e = __expf(v - m);
    float s = grpsum16(e);
    sPi[grp * 16 + a] = e * __builtin_amdgcn_rcpf(s);
  }
  // ---- B softmax over axis 1 (M): row c = grp, lane a covers m = a+16k ----
  {
    const int c = grp;
    float vv[16];
    float mx = -1e30f;
    #pragma unroll
    for (int k = 0; k < 16; ++k) {
      vv[k] = lB[c * (256 * G_) + (a + 16 * k) * G_ + g];
      mx = fmaxf(mx, vv[k]);
    }
    mx = grpmax16(mx);
    float ssum = 0.f;
    #pragma unroll
    for (int k = 0; k < 16; ++k) { vv[k] = __expf(vv[k] - mx); ssum += vv[k]; }
    ssum = grpsum16(ssum);
    float is = __builtin_amdgcn_rcpf(ssum);
    #pragma unroll
    for (int k = 0; k < 16; ++k) sB[(a + 16 * k) * 17 + c] = vv[k] * is;
  }
  __syncthreads();

  // ---- per-lane rotated weight vectors: w[r] = A[a][(a-r)&15][l] * SP[l] ----
  f16v w0, w1;
  #pragma unroll
  for (int r = 0; r < 16; ++r) {
    int b = (a - r) & 15;
    w0[r] = sA[b * 16 + a] * SP0;
    w1[r] = sA[(16 + b) * 16 + a] * SP1;
  }
  const float pi0 = sPi[a], pi1 = sPi[16 + a];
  const float* sBa = sB + a;

  // ---- observation indices, pre-scaled by 17 and packed (x<256 => <16b) ----
  int lxA = x[base + 511 + 16 * grp + a] * 17;
  int lxB = x[base + 511 + 16 * (grp + 16) + a] * 17;
  int leafp = lxA | (lxB << 16);
  int dpl = 31 - __clz(a + 1);
  int iA = (a < 15) ? x[base + ((31 + grp) << dpl) + a] * 17 : 0;
  int iB = (a < 15) ? x[base + ((31 + grp + 16) << dpl) + a] * 17 : 0;
  int intp = iA | (iB << 16);

  // ---- hoist all 32 leaf gathers: pipelined bpermute+LDS reads up front ----
  f16v lfx, lfy;
  #pragma unroll
  for (int j = 0; j < 16; ++j) {
    int xp = __shfl(leafp, j, 16);
    float pi = (j & 1) ? pi1 : pi0;
    lfx[j] = pi * sBa[xp & 0xFFFF];
    lfy[j] = pi * sBa[((unsigned)xp) >> 16];
  }

  float2 ll = {0.f, 0.f};
  float2 rraw, rrcp;
  evalN<0, 0>(sBa, w0, w1, lfx, lfy, intp, ll, rraw, rrcp);
  roots[grp * 17 + a]        = rraw.x * rrcp.x;
  roots[(grp + 16) * 17 + a] = rraw.y * rrcp.y;
  __syncthreads();

  // ---- top 31 nodes (levels 4..0) ----
  float llt = 0.f;
  int tl = tid & 63;
  int topx = x[base + (tl < 31 ? tl : 0)];           // x[0..30] in wave lanes

  topStep(roots, topA, 16, 4, sB, w0, w1, a, grp, topx, llt);
  topStep(topA, topB, 8, 3, sB, w0, w1, a, grp, topx, llt);
  topStep(topB, topA, 4, 2, sB, w0, w1, a, grp, topx, llt);
  topStep(topA, topB, 2, 1, sB, w0, w1, a, grp, topx, llt);
  topStep(topB, nullptr, 1, 0, sB, w0, w1, a, grp, topx, llt);

  // ---- block reduce; scale: x16 lane duplication and log2 -> ln ----
  float v = ll.x + ll.y + llt;
  #pragma unroll
  for (int off = 32; off > 0; off >>= 1) v += __shfl_down(v, off, 64);
  if ((tid & 63) == 0) red[tid >> 6] = v;
  __syncthreads();
  if (tid == 0)
    out[bid] = (red[0] + red[1] + red[2] + red[3]) * (0.6931471805599453f / 16.f);
}

extern "C" void kernel_launch(void* const* d_in, const int* in_sizes, int n_in,
                              void* d_out, int out_size, void* d_ws, size_t ws_size,
                              hipStream_t stream) {
  const float* lA  = (const float*)d_in[0];
  const float* lB  = (const float*)d_in[1];
  const float* lPi = (const float*)d_in[2];
  const float* lSP = (const float*)d_in[3];
  const int*   x   = (const int*)d_in[4];
  float* out = (float*)d_out;
  htmm_fwd_kernel<<<dim3(NT_ * G_), dim3(256), 0, stream>>>(lA, lB, lPi, lSP, x, out);
}